// Round 2
// baseline (115.643 us; speedup 1.0000x reference)
//
#include <hip/hip_runtime.h>

#define FDIM 32
#define NNODES 255
#define NLEAVES 256
#define RS 36   // LDS row stride in floats: 32 W + c + 3 pad = 144 B (16B aligned)

__device__ __forceinline__ float fast_sigmoid(float z) {
    // 1/(1+exp(-z)); __expf -> v_exp_f32, rcp -> v_rcp_f32 (approx, ~1 ulp)
    float e = __expf(-z);
    return __builtin_amdgcn_rcpf(1.0f + e);
}

// g for one node: dot(x, W[node]) - c[node], sigmoid.
// W lives in LDS; node is wave-uniform -> ds_read broadcast, conflict-free,
// base addr = s_mul + v_mov, per-read 16B offsets fold into ds_read imm.
__device__ __forceinline__ float node_g(const float* __restrict__ sW,
                                        const float (&xr)[FDIM], int node) {
    const float* w = sW + node * RS;
    float z0 = -w[32], z1 = 0.f, z2 = 0.f, z3 = 0.f;
#pragma unroll
    for (int q = 0; q < 8; ++q) {
        float4 v = ((const float4*)w)[q];
        z0 = fmaf(xr[4*q+0], v.x, z0);
        z1 = fmaf(xr[4*q+1], v.y, z1);
        z2 = fmaf(xr[4*q+2], v.z, z2);
        z3 = fmaf(xr[4*q+3], v.w, z3);
    }
    return fast_sigmoid((z0 + z1) + (z2 + z3));
}

// Precompute Wr = relu(feature_importances), c = sum(Wr * sigmoid(feature_splits))
__global__ void dtree_prep(const float* __restrict__ fi, const float* __restrict__ fs,
                           float* __restrict__ W, float* __restrict__ c) {
    int node = threadIdx.x;
    if (node < NNODES) {
        float s = 0.f;
#pragma unroll
        for (int k = 0; k < FDIM; ++k) {
            float w = fi[(node << 5) + k];
            w = w > 0.f ? w : 0.f;
            float sg = fast_sigmoid(fs[(node << 5) + k]);
            W[(node << 5) + k] = w;
            s = fmaf(w, sg, s);
        }
        c[node] = s;
    }
}

// Block = 512 threads = 8 waves. 256 samples/block; threads [0,256) walk the
// LEFT 127-node subtree (root node 1), threads [256,512) the RIGHT (node 2).
// half = tid>>8 is wave-uniform -> all node indices stay wave-uniform.
__global__ __launch_bounds__(512, 4) void dtree_main(const float* __restrict__ x,
                                                     const float* __restrict__ Wg,
                                                     const float* __restrict__ cg,
                                                     const float* __restrict__ cls,
                                                     float* __restrict__ out) {
    __shared__ float sW[256 * RS];     // 36864 B
    __shared__ float scls[NLEAVES];    // 1024 B
    __shared__ float spart[256];       // 1024 B

    const int tid = threadIdx.x;

    // Stage W (coalesced float4) into padded rows, c at col 32, cls.
    for (int j = tid; j < NNODES * 8; j += 512) {
        int row = j >> 3, q = j & 7;
        float4 v = ((const float4*)Wg)[j];
        *((float4*)(sW + row * RS + 4 * q)) = v;
    }
    if (tid < NNODES) sW[tid * RS + 32] = cg[tid];
    if (tid < 64) ((float4*)scls)[tid] = ((const float4*)cls)[tid];
    __syncthreads();

    const int s = tid & 255;
    const int half = tid >> 8;         // 0 = left subtree, 1 = right
    const int n = blockIdx.x * 256 + s;

    float xr[FDIM];
    const float4* xp = (const float4*)(x + (size_t)n * FDIM);
#pragma unroll
    for (int q = 0; q < 8; ++q) {
        float4 v = xp[q];
        xr[4*q+0] = v.x; xr[4*q+1] = v.y;
        xr[4*q+2] = v.z; xr[4*q+3] = v.w;
    }

    // Root (duplicated in both halves): leaf bit7; pbit=1 -> factor (1-g).
    float g0 = node_g(sW, xr, 0);
    float p0 = half ? (1.f - g0) : g0;
    const int R = 1 + half;            // this half's subtree root (level 1)

    float acc = 0.f;
    float gA, gB, gC, pA, pB, pC;      // cached g/p along current prefix path
    int nB, nC;

    // i = 3-bit prefix (levels 1..3 directions within the subtree, MSB first).
    for (int i = 0; i < 8; ++i) {
        if (i == 0) {
            gA = node_g(sW, xr, R);   pA = p0 * gA;
            nB = 2*R + 1;  gB = node_g(sW, xr, nB);  pB = pA * gB;
            nC = 2*nB + 1; gC = node_g(sW, xr, nC);  pC = pB * gC;
        } else {
            int t = __builtin_ctz(i);
            if (t == 0) {              // only lowest bit flips L->R
                pC = pB * (1.f - gC);
            } else if (t == 1) {
                pB = pA * (1.f - gB);
                nC = 2*nB + 2; gC = node_g(sW, xr, nC); pC = pB * gC;
            } else {                   // t == 2 (i == 4)
                pA = p0 * (1.f - gA);
                nB = 2*R + 2;  gB = node_g(sW, xr, nB); pB = pA * gB;
                nC = 2*nB + 1; gC = node_g(sW, xr, nC); pC = pB * gC;
            }
        }
        // Bottom 4 levels under nD: 15 nodes, fully unrolled, static regs.
        int nD = 2*nC + 1 + (i & 1);
        float gD = node_g(sW, xr, nD);
#pragma unroll
        for (int b4 = 0; b4 < 2; ++b4) {
            float p4 = pC * (b4 ? (1.f - gD) : gD);
            int nE = 2*nD + 1 + b4;
            float gE = node_g(sW, xr, nE);
#pragma unroll
            for (int b5 = 0; b5 < 2; ++b5) {
                float p5 = p4 * (b5 ? (1.f - gE) : gE);
                int nF = 2*nE + 1 + b5;
                float gF = node_g(sW, xr, nF);
#pragma unroll
                for (int b6 = 0; b6 < 2; ++b6) {
                    float p6 = p5 * (b6 ? (1.f - gF) : gF);
                    int nG = 2*nF + 1 + b6;
                    float gG = node_g(sW, xr, nG);
                    int lb = half * 128 + i * 16 + b4 * 8 + b5 * 4 + b6 * 2;
                    float c0 = scls[lb], c1 = scls[lb + 1];
                    // p6 * (g*c0 + (1-g)*c1) = p6 * fma(g, c0-c1, c1)
                    acc = fmaf(p6, fmaf(gG, c0 - c1, c1), acc);
                }
            }
        }
    }

    if (half == 0) spart[s] = acc;
    __syncthreads();
    if (half == 1) out[n] = spart[s] + acc;
}

extern "C" void kernel_launch(void* const* d_in, const int* in_sizes, int n_in,
                              void* d_out, int out_size, void* d_ws, size_t ws_size,
                              hipStream_t stream) {
    const float* x   = (const float*)d_in[0];
    const float* fi  = (const float*)d_in[1];
    const float* fs  = (const float*)d_in[2];
    const float* cls = (const float*)d_in[3];

    float* W = (float*)d_ws;              // 255*32 floats
    float* c = W + NNODES * FDIM;         // 255 floats

    int nsamp = in_sizes[0] / FDIM;
    float* out = (float*)d_out;

    hipLaunchKernelGGL(dtree_prep, dim3(1), dim3(256), 0, stream, fi, fs, W, c);
    hipLaunchKernelGGL(dtree_main, dim3(nsamp / 256), dim3(512), 0, stream,
                       x, W, c, cls, out);
}

// Round 3
// 44.906 us; speedup vs baseline: 2.5752x; 2.5752x over previous
//
#include <hip/hip_runtime.h>

#define FDIM 32
#define NNODES 255
#define NLEAVES 256
#define LOG2E 1.44269504088896340f

typedef _Float16 half8  __attribute__((ext_vector_type(8)));
typedef _Float16 half4v __attribute__((ext_vector_type(4)));
typedef _Float16 half2v __attribute__((ext_vector_type(2)));
typedef float    f32x4  __attribute__((ext_vector_type(4)));

__device__ __forceinline__ float fsig(float z) {
    // sigmoid(z) = 1/(1 + 2^(-z*log2e)); v_exp_f32 + v_rcp_f32
    return __builtin_amdgcn_rcpf(1.0f + __builtin_amdgcn_exp2f(-z * LOG2E));
}

// Prep: slot = node+1 (slot 0 dummy). Wh[slot][32] f16 relu'd weights,
// negc[slot] = -sum(relu(W)*sigmoid(S)), Dtab[y] = {cls[2y]-cls[2y+1], cls[2y+1]}.
__global__ void dtree_prep(const float* __restrict__ fi, const float* __restrict__ fs,
                           const float* __restrict__ cls,
                           _Float16* __restrict__ Wh, float* __restrict__ negc,
                           float* __restrict__ Dtab) {
    int t = threadIdx.x;   // 0..255
    if (t < 128) {
        float c0 = cls[2 * t], c1 = cls[2 * t + 1];
        Dtab[2 * t]     = c0 - c1;
        Dtab[2 * t + 1] = c1;
    }
    if (t == 0) {
#pragma unroll
        for (int k = 0; k < FDIM; ++k) Wh[k] = (_Float16)0.0f;
        negc[0] = 0.0f;
    } else {
        int node = t - 1;
        float s = 0.0f;
#pragma unroll
        for (int k = 0; k < FDIM; ++k) {
            float w = fi[(node << 5) + k];
            w = w > 0.0f ? w : 0.0f;
            Wh[(t << 5) + k] = (_Float16)w;
            s = fmaf(w, fsig(fs[(node << 5) + k]), s);
        }
        negc[t] = -s;
    }
}

// Fused: per wave, 16 samples. Phase 1: 16 MFMAs (A=W rows=slots, B=x cols=samples,
// C-init=-c) -> sigmoid -> f16 g into per-wave LDS [16][264]. Phase 2: tree walk,
// 4 lanes per sample x 4 subtrees per lane, contiguous-slot vector LDS reads.
__global__ __launch_bounds__(256, 4) void dtree_fused(
    const float* __restrict__ x, const _Float16* __restrict__ Wh,
    const float* __restrict__ negc, const float* __restrict__ Dtab,
    float* __restrict__ out)
{
    __shared__ __align__(16) _Float16 gbuf[4][16][264];   // 33792 B

    const int tid = threadIdx.x;
    const int w = tid >> 6;          // wave in block
    const int l = tid & 63;          // lane
    const int s = l & 15;            // sample col (phase1) / sample (phase2)
    const int h = l >> 4;            // 16-lane group
    const int n = blockIdx.x * 64 + w * 16 + s;

    // ---- Phase 1: B fragment = x[n][8h..8h+7] as f16 ----
    const float* xrow = x + (size_t)n * FDIM + 8 * h;
    f32x4 xv0 = *(const f32x4*)(xrow);
    f32x4 xv1 = *(const f32x4*)(xrow + 4);
    half8 bfrag;
    bfrag[0] = (_Float16)xv0[0]; bfrag[1] = (_Float16)xv0[1];
    bfrag[2] = (_Float16)xv0[2]; bfrag[3] = (_Float16)xv0[3];
    bfrag[4] = (_Float16)xv1[0]; bfrag[5] = (_Float16)xv1[1];
    bfrag[6] = (_Float16)xv1[2]; bfrag[7] = (_Float16)xv1[3];

    _Float16* gsw = &gbuf[w][s][0];

#pragma unroll 4
    for (int m = 0; m < 16; ++m) {
        // A fragment: row = l&15 -> slot = 16m + s ; k = 8h..8h+7
        half8 afrag = *(const half8*)(Wh + ((16 * m + s) << 5) + 8 * h);
        // C-in: -c for rows 16m+4h..+3 (C layout: row = 4h+r, col = s)
        f32x4 cin = *(const f32x4*)(negc + 16 * m + 4 * h);
        f32x4 acc = __builtin_amdgcn_mfma_f32_16x16x32_f16(afrag, bfrag, cin, 0, 0, 0);
        half4v hg;
        hg[0] = (_Float16)fsig(acc[0]);
        hg[1] = (_Float16)fsig(acc[1]);
        hg[2] = (_Float16)fsig(acc[2]);
        hg[3] = (_Float16)fsig(acc[3]);
        *(half4v*)(gsw + 16 * m + 4 * h) = hg;   // g[s][16m+4h .. +3]
    }

    __syncthreads();   // cross-lane LDS visibility (phase2 reads other lanes' writes)

    // ---- Phase 2: walk. lane handles sample s, subtrees i = 4h+j (j=0..3) ----
    const _Float16* gs = gsw;
    float g1  = (float)gs[1];                         // root (level 0)
    float gP2 = (float)gs[2 + (h >> 1)];              // level 1, slot 2+(i>>3)
    float gP3 = (float)gs[4 + h];                     // level 2, slot 4+(i>>2)=4+h
    half2v p4p = *(const half2v*)(gs + 8 + 2 * h);    // level 3 slots 8+2h, 9+2h
    float gP4a = (float)p4p[0], gP4b = (float)p4p[1];
    half4v dDv = *(const half4v*)(gs + 16 + 4 * h);   // level 4: slots 16+4h..+3
    half8  dEv = *(const half8*)(gs + 32 + 8 * h);    // level 5: slots 32+8h..+7
    half8  dF0 = *(const half8*)(gs + 64 + 16 * h);   // level 6: slots 64+16h..+15
    half8  dF1 = *(const half8*)(gs + 64 + 16 * h + 8);

    float f0 = (h & 2) ? 1.0f - g1  : g1;             // bit0 of leaf-prefix = i>>3
    float f1 = (h & 1) ? 1.0f - gP2 : gP2;            // bit1 = (i>>2)&1 = h&1
    float f01 = f0 * f1;

    const f32x4* dtb = (const f32x4*)Dtab;
    float facc = 0.0f;

#pragma unroll
    for (int j = 0; j < 4; ++j) {                     // i = 4h + j
        float f2 = (j & 2) ? 1.0f - gP3 : gP3;        // bit2 = (i>>1)&1 = j>>1
        float gP4 = (j & 2) ? gP4b : gP4a;            // slot 8+(i>>1)
        float f3 = (j & 1) ? 1.0f - gP4 : gP4;        // bit3 = i&1 = j&1
        float p4 = f01 * (f2 * f3);
        float gD = (float)dDv[j];                     // slot 16+i
        half8 dG = *(const half8*)(gs + 128 + 32 * h + 8 * j); // slots 128+8i..+7
        f32x4 q0 = dtb[16 * h + 4 * j + 0];           // leaf-pair table y=8i..8i+7
        f32x4 q1 = dtb[16 * h + 4 * j + 1];
        f32x4 q2 = dtb[16 * h + 4 * j + 2];
        f32x4 q3 = dtb[16 * h + 4 * j + 3];
#pragma unroll
        for (int b4 = 0; b4 < 2; ++b4) {
            float p5 = b4 ? (p4 - p4 * gD) : (p4 * gD);
            float gE = (float)dEv[2 * j + b4];        // slot 32+2i+b4
#pragma unroll
            for (int b5 = 0; b5 < 2; ++b5) {
                float p6 = b5 ? (p5 - p5 * gE) : (p5 * gE);
                float gF = (float)((j & 2) ? dF1[4 * (j & 1) + 2 * b4 + b5]
                                           : dF0[4 * (j & 1) + 2 * b4 + b5]);
#pragma unroll
                for (int b6 = 0; b6 < 2; ++b6) {
                    float p7 = b6 ? (p6 - p6 * gF) : (p6 * gF);
                    int t = 4 * b4 + 2 * b5 + b6;     // static
                    float gG = (float)dG[t];
                    f32x4 q = (t < 2) ? q0 : (t < 4) ? q1 : (t < 6) ? q2 : q3;
                    float D0 = (t & 1) ? q[2] : q[0];
                    float D1 = (t & 1) ? q[3] : q[1];
                    facc = fmaf(p7, fmaf(gG, D0, D1), facc);
                }
            }
        }
    }

    // combine the 4 h-lanes of each sample
    facc += __shfl_xor(facc, 16, 64);
    facc += __shfl_xor(facc, 32, 64);
    if (h == 0) out[n] = facc;
}

extern "C" void kernel_launch(void* const* d_in, const int* in_sizes, int n_in,
                              void* d_out, int out_size, void* d_ws, size_t ws_size,
                              hipStream_t stream) {
    const float* x   = (const float*)d_in[0];
    const float* fi  = (const float*)d_in[1];
    const float* fs  = (const float*)d_in[2];
    const float* cls = (const float*)d_in[3];

    _Float16* Wh = (_Float16*)d_ws;                        // 256*32*2 = 16 KB
    float* negc  = (float*)((char*)d_ws + 16384);          // 1 KB
    float* Dtab  = negc + 256;                             // 1 KB

    int nsamp = in_sizes[0] / FDIM;                        // 262144
    float* out = (float*)d_out;

    hipLaunchKernelGGL(dtree_prep, dim3(1), dim3(256), 0, stream, fi, fs, cls, Wh, negc, Dtab);
    hipLaunchKernelGGL(dtree_fused, dim3(nsamp / 64), dim3(256), 0, stream,
                       x, Wh, negc, Dtab, out);
}